// Round 10
// baseline (282.168 us; speedup 1.0000x reference)
//
#include <hip/hip_runtime.h>
#include <cmath>

#define BB  1024
#define TT  128
#define HH1 512
#define HH2 256
#define CC  18

// d_ws layout (byte offsets)
#define WS_DIG   0ull             // W2 digits: 8x4x16x2x32x16 i8 = 512 KB
#define WS_W3D   524288ull        // W3 digits LDS image: 32 KB
#define WS_MASK  557056ull        // s1 masks[t][row][8 u64] = 8 MB
#define WS_MASK2 8945664ull       // s2 masks[t][row][8 u32] = 4 MB
#define WS_D3    13139968ull      // D3[t][row][c<18] fp32 = 9.4 MB (end ~22.6 MB)

typedef int  v4i  __attribute__((ext_vector_type(4)));
typedef int  v16i __attribute__((ext_vector_type(16)));
typedef unsigned long long ull;

__device__ __forceinline__ v4i expand_bits(unsigned bits) {
  v4i a;
  a.x = (int)((( bits        & 15u) * 0x204081u) & 0x01010101u);
  a.y = (int)((((bits >>  4) & 15u) * 0x204081u) & 0x01010101u);
  a.z = (int)((((bits >>  8) & 15u) * 0x204081u) & 0x01010101u);
  a.w = (int)((((bits >> 12) & 15u) * 0x204081u) & 0x01010101u);
  return a;
}

// ---- merged front end: W2 digits | W3 digits | bit-exact layer-1 masks.
__global__ __launch_bounds__(256) void phase_front(const float* __restrict__ W2,
    const float* __restrict__ W3, const float* __restrict__ x,
    const float* __restrict__ W1, const float* __restrict__ b1,
    signed char* __restrict__ dig, signed char* __restrict__ w3d,
    ull* __restrict__ masks)
{
  const int blk = blockIdx.x, tid = threadIdx.x;
  if (blk < 2048) {
    // W2 -> 4 signed-i8 digit planes of llrint(w*2^32), layout
    // [stripe(8)][d(4)][s(16)][h(2)][n(32)][j(16)]; h1=s*32+h*16+j, h2=stripe*32+n
    int i = blk * 256 + tid;                       // [0, 524288)
    int j = i & 15, n = (i >> 4) & 31, h = (i >> 9) & 1;
    int s = (i >> 10) & 15, d = (i >> 14) & 3, st = i >> 16;
    int h1 = s * 32 + h * 16 + j;
    int h2 = st * 32 + n;
    float w = W2[h2 * HH1 + h1];
    long long ll = llrint((double)w * 4294967296.0);
    int v = (int)ll;
    signed char d0 = (signed char)(v & 255); v = (v - d0) >> 8;
    signed char d1 = (signed char)(v & 255); v = (v - d1) >> 8;
    signed char d2 = (signed char)(v & 255); v = (v - d2) >> 8;
    signed char d3 = (signed char)v;
    dig[i] = (d == 0) ? d0 : (d == 1) ? d1 : (d == 2) ? d2 : d3;
  } else if (blk < 2176) {
    // W3 digits, LDS image [d(4)][c8(8)][h(2)][col(32)][j(16)], 32 KB
    int i = (blk - 2048) * 256 + tid;              // [0, 32768)
    int j = i & 15, col = (i >> 4) & 31, h = (i >> 9) & 1;
    int c8 = (i >> 10) & 7, d = (i >> 13) & 3;
    int h2 = c8 * 32 + h * 16 + j;
    float w = (col < CC) ? W3[col * HH2 + h2] : 0.0f;
    long long ll = llrint((double)w * 4294967296.0);
    int v = (int)ll;
    signed char d0 = (signed char)(v & 255); v = (v - d0) >> 8;
    signed char d1 = (signed char)(v & 255); v = (v - d1) >> 8;
    signed char d2 = (signed char)(v & 255); v = (v - d2) >> 8;
    signed char d3 = (signed char)v;
    w3d[i] = (d == 0) ? d0 : (d == 1) ? d1 : (d == 2) ? d2 : d3;
  } else {
    // bit-exact layer 1 (mul-rn, add-rn, add-rn), one block per row
    __shared__ float xrow[TT];
    const int row = blk - 2176, wv = tid >> 6, lane = tid & 63;
    for (int i = tid; i < TT; i += 256) xrow[i] = x[row * TT + i];
    const float w1a = W1[tid], w1b = W1[tid + 256];
    const float b1a = b1[tid], b1b = b1[tid + 256];
    float v1a = 0.f, v1b = 0.f;
    __syncthreads();
    for (int t = 0; t < TT; ++t) {
      float xt = xrow[t];
      float iA = __fadd_rn(__fmul_rn(xt, w1a), b1a);
      v1a = __fadd_rn(v1a, iA);
      bool sA = (v1a >= 1.0f);  v1a = sA ? (v1a - 1.0f) : v1a;
      float iB = __fadd_rn(__fmul_rn(xt, w1b), b1b);
      v1b = __fadd_rn(v1b, iB);
      bool sB = (v1b >= 1.0f);  v1b = sB ? (v1b - 1.0f) : v1b;
      ull mA = __ballot(sA);
      ull mB = __ballot(sB);
      if (lane == 0) {
        ull* p = masks + ((size_t)t * BB + row) * 8;
        p[wv] = mA; p[4 + wv] = mB;
      }
    }
  }
}

// ---- fused layer 2, digit-specialized register-resident-B version.
// 512 threads = 8 waves. Waves 0-3: wave wv owns digit plane wv; entire B slab
// (16 s x 4 VGPR) loaded ONCE into registers -> zero LDS/global B traffic in
// the K-loop. Per 4-t chunk: 64 MFMA/wave into 4x v16i acc; raw i32 partials
// to pbuf[c&1]. Waves 4-7: fold 4 digit partials exactly (i32 -> f64 fma ->
// one f32 rounding, bit-identical to R4 path) + v2 scan + s2 ballot masks.
__global__ __launch_bounds__(512) void phase_gemmscan(
    const signed char* __restrict__ Bd, const ull* __restrict__ masks,
    const float* __restrict__ b2, unsigned* __restrict__ masks2)
{
  __shared__ int pbuf[2][4][4][1024];              // [dbuf][tl][digit][row*32+col] 128 KB

  const int bid = blockIdx.x;
  const int rowtile = bid & 31, stripe = bid >> 5; // stripe-siblings: same XCD
  const int tid = threadIdx.x, lane = tid & 63, wv = tid >> 6;
  const int half = lane >> 5;

  // GEMM-wave constants (wv < 4): digit plane = wv
  const int arow = rowtile * 32 + (lane & 31);
  const int hsh  = half * 16;
  v4i breg[16];
  if (wv < 4) {
    const signed char* bsrc = Bd + (size_t)stripe * 65536 + wv * 16384
                               + half * 512 + (lane & 31) * 16;
#pragma unroll
    for (int s = 0; s < 16; ++s)
      breg[s] = *(const v4i*)(bsrc + s * 1024);
  }

  // scan-wave constants (wv >= 4)
  const int stid = tid - 256;                      // 0..255 for waves 4-7
  const int scol = stid & 31, sgrp = stid >> 5;    // col, 4-row group
  float v2[4] = {0.f, 0.f, 0.f, 0.f};
  float b2r = 0.f;
  if (wv >= 4) b2r = b2[stripe * 32 + scol];

  __syncthreads();

  for (int c = 0; c <= 32; ++c) {
    if (wv < 4 && c < 32) {
      // ---- GEMM: 4 t, digit plane wv, B in registers ----
      ull wt[4][8];
#pragma unroll
      for (int tt = 0; tt < 4; ++tt) {
        const ull* p = masks + ((size_t)(c * 4 + tt) * BB + arow) * 8;
#pragma unroll
        for (int k = 0; k < 8; ++k) wt[tt][k] = p[k];
      }
      v16i acc[4];
#pragma unroll
      for (int tt = 0; tt < 4; ++tt)
        acc[tt] = (v16i){0,0,0,0,0,0,0,0,0,0,0,0,0,0,0,0};
#pragma unroll
      for (int s = 0; s < 16; ++s) {
        unsigned shift = ((s & 1) << 5) + hsh;
#pragma unroll
        for (int tt = 0; tt < 4; ++tt) {
          v4i a = expand_bits((unsigned)(wt[tt][s >> 1] >> shift) & 0xFFFFu);
          acc[tt] = __builtin_amdgcn_mfma_i32_32x32x32_i8(a, breg[s], acc[tt], 0, 0, 0);
        }
      }
      // raw i32 partials; fold happens in the scan waves
#pragma unroll
      for (int tt = 0; tt < 4; ++tt)
#pragma unroll
        for (int r = 0; r < 16; ++r) {
          int rowl = (r & 3) + 8 * (r >> 2) + 4 * half;
          pbuf[c & 1][tt][wv][rowl * 32 + (lane & 31)] = acc[tt][r];
        }
    }
    if (wv >= 4 && c > 0) {
      // ---- scan chunk c-1: fold digits + v2 recurrence + s2 masks ----
      const int rb = (c - 1) & 1;
      const int tb = (c - 1) * 4;
#pragma unroll
      for (int tl = 0; tl < 4; ++tl) {
        const int t = tb + tl;
#pragma unroll
        for (int q = 0; q < 4; ++q) {
          const int cell = (sgrp * 4 + q) * 32 + scol;
          int p0 = pbuf[rb][tl][0][cell];
          int p1 = pbuf[rb][tl][1][cell];
          int p2 = pbuf[rb][tl][2][cell];
          int p3 = pbuf[rb][tl][3][cell];
          int slo = p0 + (p1 << 8);                // exact i32, |.| < 2^25
          int shi = p2 + (p3 << 8);                // exact i32, |.| < 2^21
          double ss = fma((double)shi, 65536.0, (double)slo);   // exact
          float d2 = (float)(ss * 0x1p-32);                     // one rounding
          float i2 = __fadd_rn(d2, b2r);
          v2[q] = __fadd_rn(v2[q], i2);
          bool s2 = (v2[q] >= 1.0f);
          v2[q] = s2 ? (v2[q] - 1.0f) : v2[q];
          ull m = __ballot(s2);                    // lo32: even sgrp, hi32: odd
          if (lane == 0)
            masks2[((size_t)t * BB + rowtile * 32 + sgrp * 4 + q) * 8 + stripe]
                = (unsigned)m;
          else if (lane == 32)
            masks2[((size_t)t * BB + rowtile * 32 + sgrp * 4 + q) * 8 + stripe]
                = (unsigned)(m >> 32);
        }
      }
    }
    __syncthreads();
  }
}

// ---- layer 3: D3[t] = S2[t] @ W3^T, exact i8 MFMA. Block: 32 rows x 4 t.
__global__ __launch_bounds__(256) void phase_l3(const signed char* __restrict__ W3d,
    const unsigned* __restrict__ masks2, float* __restrict__ D3)
{
  __shared__ __align__(16) signed char Bl[32768];
  const int bid = blockIdx.x;
  const int rowtile = bid & 31, tgrp = bid >> 5;
  const int tid = threadIdx.x, lane = tid & 63, wv = tid >> 6;
  const int half = lane >> 5;
  const int t = tgrp * 4 + wv;
  const int row = rowtile * 32 + (lane & 31);

  {
    const uint4* src = (const uint4*)W3d;
    uint4* dst = (uint4*)Bl;
#pragma unroll
    for (int i = 0; i < 8; ++i) dst[tid + 256 * i] = src[tid + 256 * i];
  }

  unsigned words[8];
  {
    const unsigned* mp = masks2 + ((size_t)t * BB + row) * 8;
#pragma unroll
    for (int k = 0; k < 8; ++k) words[k] = mp[k];
  }
  __syncthreads();

  const signed char* bbase = Bl + half * 512 + (lane & 31) * 16;
  v16i acc[4];
#pragma unroll
  for (int d = 0; d < 4; ++d) acc[d] = (v16i){0,0,0,0,0,0,0,0,0,0,0,0,0,0,0,0};

#pragma unroll
  for (int c8 = 0; c8 < 8; ++c8) {
    v4i a = expand_bits((words[c8] >> (half * 16)) & 0xFFFFu);
#pragma unroll
    for (int d = 0; d < 4; ++d) {
      v4i b = *(const v4i*)(bbase + ((d * 8 + c8) * 2) * 512);
      acc[d] = __builtin_amdgcn_mfma_i32_32x32x32_i8(a, b, acc[d], 0, 0, 0);
    }
  }

  const int col = lane & 31;
#pragma unroll
  for (int r = 0; r < 16; ++r) {
    int slo = acc[0][r] + (acc[1][r] << 8);
    int shi = acc[2][r] + (acc[3][r] << 8);
    double ss = fma((double)shi, 65536.0, (double)slo);
    float d3v = (float)(ss * 0x1p-32);
    int rowl = (r & 3) + 8 * (r >> 2) + 4 * half;
    int grow = rowtile * 32 + rowl;
    if (col < CC) D3[((size_t)t * BB + grow) * CC + col] = d3v;
  }
}

// ---- v3/acc scan + output. thread=(row,c); 4-deep prefetch ring; grid 72.
__global__ __launch_bounds__(256) void phase_v3(const float* __restrict__ D3,
    const float* __restrict__ b3, float* __restrict__ out)
{
  int g = blockIdx.x * 256 + threadIdx.x;         // [0, 18432)
  int row = g / CC, c = g - row * CC;
  const float b3r = b3[c];
  float v3 = 0.f, acc = 0.f;
  float buf[4];
#pragma unroll
  for (int p = 0; p < 4; ++p) buf[p] = D3[(size_t)p * (BB * CC) + g];
  for (int t = 0; t < TT; ++t) {
    float d3 = buf[t & 3];
    if (t + 4 < TT) buf[t & 3] = D3[(size_t)(t + 4) * (BB * CC) + g];
    float i3 = __fadd_rn(d3, b3r);
    v3 = __fadd_rn(v3, i3);
    bool s3 = (v3 >= 1.0f);  v3 = s3 ? (v3 - 1.0f) : v3;
    acc = __fadd_rn(acc, s3 ? 1.0f : 0.0f);
  }
  out[g] = acc * (1.0f / TT);
}

extern "C" void kernel_launch(void* const* d_in, const int* in_sizes, int n_in,
                              void* d_out, int out_size, void* d_ws, size_t ws_size,
                              hipStream_t stream)
{
  (void)in_sizes; (void)n_in; (void)out_size; (void)ws_size;
  const float* x  = (const float*)d_in[0];
  const float* W1 = (const float*)d_in[1];
  const float* b1 = (const float*)d_in[2];
  const float* W2 = (const float*)d_in[3];
  const float* b2 = (const float*)d_in[4];
  const float* W3 = (const float*)d_in[5];
  const float* b3 = (const float*)d_in[6];
  // d_in[7] = repeat (structurally 1 for this problem shape)
  float* out = (float*)d_out;
  char*  ws  = (char*)d_ws;

  signed char* dig    = (signed char*)(ws + WS_DIG);
  signed char* w3dig  = (signed char*)(ws + WS_W3D);
  ull*         masks  = (ull*)(ws + WS_MASK);
  unsigned*    masks2 = (unsigned*)(ws + WS_MASK2);
  float*       D3     = (float*)(ws + WS_D3);

  phase_front<<<3200, 256, 0, stream>>>(W2, W3, x, W1, b1, dig, w3dig, masks);
  phase_gemmscan<<<256, 512, 0, stream>>>(dig, masks, b2, masks2);
  phase_l3<<<1024, 256, 0, stream>>>(w3dig, masks2, D3);
  phase_v3<<<72, 256, 0, stream>>>(D3, b3, out);
}

// Round 11
// 272.895 us; speedup vs baseline: 1.0340x; 1.0340x over previous
//
#include <hip/hip_runtime.h>
#include <cmath>

#define BB  1024
#define TT  128
#define HH1 512
#define HH2 256
#define CC  18

// d_ws layout (byte offsets)
#define WS_DIG   0ull             // W2 digits: 8x4x16x2x32x16 i8 = 512 KB
#define WS_W3D   524288ull        // W3 digits LDS image: 32 KB
#define WS_MASK  557056ull        // s1 masks[t][row][8 u64] = 8 MB
#define WS_MASK2 8945664ull       // s2 masks[t][row][8 u32] = 4 MB
#define WS_D3    13139968ull      // D3[t][row][c<18] fp32 = 9.4 MB (end ~22.6 MB)

typedef int  v4i  __attribute__((ext_vector_type(4)));
typedef int  v16i __attribute__((ext_vector_type(16)));
typedef unsigned long long ull;

__device__ __forceinline__ v4i expand_bits(unsigned bits) {
  v4i a;
  a.x = (int)((( bits        & 15u) * 0x204081u) & 0x01010101u);
  a.y = (int)((((bits >>  4) & 15u) * 0x204081u) & 0x01010101u);
  a.z = (int)((((bits >>  8) & 15u) * 0x204081u) & 0x01010101u);
  a.w = (int)((((bits >> 12) & 15u) * 0x204081u) & 0x01010101u);
  return a;
}

// ---- merged front end: W2 digits | W3 digits | bit-exact layer-1 masks.
__global__ __launch_bounds__(256) void phase_front(const float* __restrict__ W2,
    const float* __restrict__ W3, const float* __restrict__ x,
    const float* __restrict__ W1, const float* __restrict__ b1,
    signed char* __restrict__ dig, signed char* __restrict__ w3d,
    ull* __restrict__ masks)
{
  const int blk = blockIdx.x, tid = threadIdx.x;
  if (blk < 2048) {
    // W2 -> 4 signed-i8 digit planes of llrint(w*2^32), layout
    // [stripe(8)][d(4)][s(16)][h(2)][n(32)][j(16)]; h1=s*32+h*16+j, h2=stripe*32+n
    int i = blk * 256 + tid;                       // [0, 524288)
    int j = i & 15, n = (i >> 4) & 31, h = (i >> 9) & 1;
    int s = (i >> 10) & 15, d = (i >> 14) & 3, st = i >> 16;
    int h1 = s * 32 + h * 16 + j;
    int h2 = st * 32 + n;
    float w = W2[h2 * HH1 + h1];
    long long ll = llrint((double)w * 4294967296.0);
    int v = (int)ll;
    signed char d0 = (signed char)(v & 255); v = (v - d0) >> 8;
    signed char d1 = (signed char)(v & 255); v = (v - d1) >> 8;
    signed char d2 = (signed char)(v & 255); v = (v - d2) >> 8;
    signed char d3 = (signed char)v;
    dig[i] = (d == 0) ? d0 : (d == 1) ? d1 : (d == 2) ? d2 : d3;
  } else if (blk < 2176) {
    // W3 digits, LDS image [d(4)][c8(8)][h(2)][col(32)][j(16)], 32 KB
    int i = (blk - 2048) * 256 + tid;              // [0, 32768)
    int j = i & 15, col = (i >> 4) & 31, h = (i >> 9) & 1;
    int c8 = (i >> 10) & 7, d = (i >> 13) & 3;
    int h2 = c8 * 32 + h * 16 + j;
    float w = (col < CC) ? W3[col * HH2 + h2] : 0.0f;
    long long ll = llrint((double)w * 4294967296.0);
    int v = (int)ll;
    signed char d0 = (signed char)(v & 255); v = (v - d0) >> 8;
    signed char d1 = (signed char)(v & 255); v = (v - d1) >> 8;
    signed char d2 = (signed char)(v & 255); v = (v - d2) >> 8;
    signed char d3 = (signed char)v;
    w3d[i] = (d == 0) ? d0 : (d == 1) ? d1 : (d == 2) ? d2 : d3;
  } else {
    // bit-exact layer 1 (mul-rn, add-rn, add-rn), one block per row
    __shared__ float xrow[TT];
    const int row = blk - 2176, wv = tid >> 6, lane = tid & 63;
    for (int i = tid; i < TT; i += 256) xrow[i] = x[row * TT + i];
    const float w1a = W1[tid], w1b = W1[tid + 256];
    const float b1a = b1[tid], b1b = b1[tid + 256];
    float v1a = 0.f, v1b = 0.f;
    __syncthreads();
    for (int t = 0; t < TT; ++t) {
      float xt = xrow[t];
      float iA = __fadd_rn(__fmul_rn(xt, w1a), b1a);
      v1a = __fadd_rn(v1a, iA);
      bool sA = (v1a >= 1.0f);  v1a = sA ? (v1a - 1.0f) : v1a;
      float iB = __fadd_rn(__fmul_rn(xt, w1b), b1b);
      v1b = __fadd_rn(v1b, iB);
      bool sB = (v1b >= 1.0f);  v1b = sB ? (v1b - 1.0f) : v1b;
      ull mA = __ballot(sA);
      ull mB = __ballot(sB);
      if (lane == 0) {
        ull* p = masks + ((size_t)t * BB + row) * 8;
        p[wv] = mA; p[4 + wv] = mB;
      }
    }
  }
}

// ---- fused layer 2: digit-PAIR register-B + 2 GEMM waves/SIMD.
// 768 threads = 12 waves. Waves 0-7: pair p=wv&1 (planes 2p,2p+1; B slab
// 128 VGPRs loaded once), t-slot wv>>2... (wv>>1) owns t = c*4 + (wv>>1).
// Per chunk: 16 expands shared by 32 MFMA; exact i32 pair-fold
// acc0+(acc1<<8) -> pbuf (stride-33 pad, conflict-free b32). Waves 8-11:
// fold slo/shi exactly (f64 fma, one f32 rounding - bit-identical to R4)
// + v2 scan + s2 ballot masks. Ping-pong pbuf, 1 barrier/chunk.
__global__ __launch_bounds__(768) void phase_gemmscan(
    const signed char* __restrict__ Bd, const ull* __restrict__ masks,
    const float* __restrict__ b2, unsigned* __restrict__ masks2)
{
  __shared__ int pbuf[2][4][2][32 * 33];           // [dbuf][tl][pair][col*33+row] 67.6 KB

  const int bid = blockIdx.x;
  const int rowtile = bid & 31, stripe = bid >> 5; // stripe-siblings: same XCD
  const int tid = threadIdx.x, lane = tid & 63, wv = tid >> 6;
  const int half = lane >> 5;

  // GEMM-wave constants (wv < 8): pair p, t-slot ts
  const int p  = wv & 1;
  const int ts = wv >> 1;                          // 0..3
  const int arow = rowtile * 32 + (lane & 31);
  const int hsh  = half * 16;
  v4i breg[2][16];
  if (wv < 8) {
#pragma unroll
    for (int q = 0; q < 2; ++q) {
      const signed char* bsrc = Bd + (size_t)stripe * 65536 + (2 * p + q) * 16384
                                 + half * 512 + (lane & 31) * 16;
#pragma unroll
      for (int s = 0; s < 16; ++s)
        breg[q][s] = *(const v4i*)(bsrc + s * 1024);
    }
  }

  // scan-wave constants (wv >= 8)
  const int stid = tid - 512;                      // 0..255 for waves 8-11
  const int scol = stid & 31, sgrp = stid >> 5;    // col, 4-row group
  float v2[4] = {0.f, 0.f, 0.f, 0.f};
  float b2r = 0.f;
  if (wv >= 8) b2r = b2[stripe * 32 + scol];

  // prefetch chunk-0 masks (t = ts)
  ull pm[8];
  if (wv < 8) {
    const ull* pp = masks + ((size_t)ts * BB + arow) * 8;
#pragma unroll
    for (int k = 0; k < 8; ++k) pm[k] = pp[k];
  }

  __syncthreads();

  for (int c = 0; c <= 32; ++c) {
    if (wv < 8 && c < 32) {
      ull wt[8];
#pragma unroll
      for (int k = 0; k < 8; ++k) wt[k] = pm[k];
      // issue next-chunk mask loads now (consumed after the MFMA loop)
      const int cn = (c + 1 < 32) ? c + 1 : 31;
      { const ull* pp = masks + ((size_t)(cn * 4 + ts) * BB + arow) * 8;
#pragma unroll
        for (int k = 0; k < 8; ++k) pm[k] = pp[k]; }

      v16i acc0 = (v16i){0,0,0,0,0,0,0,0,0,0,0,0,0,0,0,0};
      v16i acc1 = (v16i){0,0,0,0,0,0,0,0,0,0,0,0,0,0,0,0};
#pragma unroll
      for (int s = 0; s < 16; ++s) {
        unsigned shift = ((s & 1) << 5) + hsh;
        v4i a = expand_bits((unsigned)(wt[s >> 1] >> shift) & 0xFFFFu);
        acc0 = __builtin_amdgcn_mfma_i32_32x32x32_i8(a, breg[0][s], acc0, 0, 0, 0);
        acc1 = __builtin_amdgcn_mfma_i32_32x32x32_i8(a, breg[1][s], acc1, 0, 0, 0);
      }
      // exact i32 pair-fold: |acc0 + 256*acc1| < 2^25 (slo) / 2^21 (shi)
      int* dst = &pbuf[c & 1][ts][p][(lane & 31) * 33];
#pragma unroll
      for (int r = 0; r < 16; ++r) {
        int rowl = (r & 3) + 8 * (r >> 2) + 4 * half;
        dst[rowl] = acc0[r] + (acc1[r] << 8);
      }
    }
    if (wv >= 8 && c > 0) {
      // ---- scan chunk c-1: exact fold + v2 recurrence + s2 masks ----
      const int rb = (c - 1) & 1;
      const int tb = (c - 1) * 4;
#pragma unroll
      for (int tl = 0; tl < 4; ++tl) {
        const int t = tb + tl;
#pragma unroll
        for (int q = 0; q < 4; ++q) {
          const int cell = scol * 33 + sgrp * 4 + q;
          int slo = pbuf[rb][tl][0][cell];         // planes 0 + (1<<8), exact
          int shi = pbuf[rb][tl][1][cell];         // planes 2 + (3<<8), exact
          double ss = fma((double)shi, 65536.0, (double)slo);   // exact
          float d2 = (float)(ss * 0x1p-32);                     // one rounding
          float i2 = __fadd_rn(d2, b2r);
          v2[q] = __fadd_rn(v2[q], i2);
          bool s2 = (v2[q] >= 1.0f);
          v2[q] = s2 ? (v2[q] - 1.0f) : v2[q];
          ull m = __ballot(s2);                    // lo32: even sgrp, hi32: odd
          if (lane == 0)
            masks2[((size_t)t * BB + rowtile * 32 + sgrp * 4 + q) * 8 + stripe]
                = (unsigned)m;
          else if (lane == 32)
            masks2[((size_t)t * BB + rowtile * 32 + sgrp * 4 + q) * 8 + stripe]
                = (unsigned)(m >> 32);
        }
      }
    }
    __syncthreads();
  }
}

// ---- layer 3: D3[t] = S2[t] @ W3^T, exact i8 MFMA. Block: 32 rows x 4 t.
__global__ __launch_bounds__(256) void phase_l3(const signed char* __restrict__ W3d,
    const unsigned* __restrict__ masks2, float* __restrict__ D3)
{
  __shared__ __align__(16) signed char Bl[32768];
  const int bid = blockIdx.x;
  const int rowtile = bid & 31, tgrp = bid >> 5;
  const int tid = threadIdx.x, lane = tid & 63, wv = tid >> 6;
  const int half = lane >> 5;
  const int t = tgrp * 4 + wv;
  const int row = rowtile * 32 + (lane & 31);

  {
    const uint4* src = (const uint4*)W3d;
    uint4* dst = (uint4*)Bl;
#pragma unroll
    for (int i = 0; i < 8; ++i) dst[tid + 256 * i] = src[tid + 256 * i];
  }

  unsigned words[8];
  {
    const unsigned* mp = masks2 + ((size_t)t * BB + row) * 8;
#pragma unroll
    for (int k = 0; k < 8; ++k) words[k] = mp[k];
  }
  __syncthreads();

  const signed char* bbase = Bl + half * 512 + (lane & 31) * 16;
  v16i acc[4];
#pragma unroll
  for (int d = 0; d < 4; ++d) acc[d] = (v16i){0,0,0,0,0,0,0,0,0,0,0,0,0,0,0,0};

#pragma unroll
  for (int c8 = 0; c8 < 8; ++c8) {
    v4i a = expand_bits((words[c8] >> (half * 16)) & 0xFFFFu);
#pragma unroll
    for (int d = 0; d < 4; ++d) {
      v4i b = *(const v4i*)(bbase + ((d * 8 + c8) * 2) * 512);
      acc[d] = __builtin_amdgcn_mfma_i32_32x32x32_i8(a, b, acc[d], 0, 0, 0);
    }
  }

  const int col = lane & 31;
#pragma unroll
  for (int r = 0; r < 16; ++r) {
    int slo = acc[0][r] + (acc[1][r] << 8);
    int shi = acc[2][r] + (acc[3][r] << 8);
    double ss = fma((double)shi, 65536.0, (double)slo);
    float d3v = (float)(ss * 0x1p-32);
    int rowl = (r & 3) + 8 * (r >> 2) + 4 * half;
    int grow = rowtile * 32 + rowl;
    if (col < CC) D3[((size_t)t * BB + grow) * CC + col] = d3v;
  }
}

// ---- v3/acc scan + output. thread=(row,c); 4-deep prefetch ring; grid 72.
__global__ __launch_bounds__(256) void phase_v3(const float* __restrict__ D3,
    const float* __restrict__ b3, float* __restrict__ out)
{
  int g = blockIdx.x * 256 + threadIdx.x;         // [0, 18432)
  int row = g / CC, c = g - row * CC;
  const float b3r = b3[c];
  float v3 = 0.f, acc = 0.f;
  float buf[4];
#pragma unroll
  for (int p = 0; p < 4; ++p) buf[p] = D3[(size_t)p * (BB * CC) + g];
  for (int t = 0; t < TT; ++t) {
    float d3 = buf[t & 3];
    if (t + 4 < TT) buf[t & 3] = D3[(size_t)(t + 4) * (BB * CC) + g];
    float i3 = __fadd_rn(d3, b3r);
    v3 = __fadd_rn(v3, i3);
    bool s3 = (v3 >= 1.0f);  v3 = s3 ? (v3 - 1.0f) : v3;
    acc = __fadd_rn(acc, s3 ? 1.0f : 0.0f);
  }
  out[g] = acc * (1.0f / TT);
}

extern "C" void kernel_launch(void* const* d_in, const int* in_sizes, int n_in,
                              void* d_out, int out_size, void* d_ws, size_t ws_size,
                              hipStream_t stream)
{
  (void)in_sizes; (void)n_in; (void)out_size; (void)ws_size;
  const float* x  = (const float*)d_in[0];
  const float* W1 = (const float*)d_in[1];
  const float* b1 = (const float*)d_in[2];
  const float* W2 = (const float*)d_in[3];
  const float* b2 = (const float*)d_in[4];
  const float* W3 = (const float*)d_in[5];
  const float* b3 = (const float*)d_in[6];
  // d_in[7] = repeat (structurally 1 for this problem shape)
  float* out = (float*)d_out;
  char*  ws  = (char*)d_ws;

  signed char* dig    = (signed char*)(ws + WS_DIG);
  signed char* w3dig  = (signed char*)(ws + WS_W3D);
  ull*         masks  = (ull*)(ws + WS_MASK);
  unsigned*    masks2 = (unsigned*)(ws + WS_MASK2);
  float*       D3     = (float*)(ws + WS_D3);

  phase_front<<<3200, 256, 0, stream>>>(W2, W3, x, W1, b1, dig, w3dig, masks);
  phase_gemmscan<<<256, 768, 0, stream>>>(dig, masks, b2, masks2);
  phase_l3<<<1024, 256, 0, stream>>>(w3dig, masks2, D3);
  phase_v3<<<72, 256, 0, stream>>>(D3, b3, out);
}

// Round 12
// 247.213 us; speedup vs baseline: 1.1414x; 1.1039x over previous
//
#include <hip/hip_runtime.h>
#include <cmath>

#define BB  1024
#define TT  128
#define HH1 512
#define HH2 256
#define CC  18

// d_ws layout (byte offsets)
#define WS_DIG   0ull             // W2 digits: 8x4x16x2x32x16 i8 = 512 KB
#define WS_W3D   524288ull        // W3 digits LDS image: 32 KB
#define WS_MASK  557056ull        // s1 masks[t][row][8 u64] = 8 MB
#define WS_MASK2 8945664ull       // s2 masks[t][row][8 u32] = 4 MB
#define WS_D3    13139968ull      // D3[t][row][c<18] fp32 = 9.4 MB (end ~22.6 MB)

typedef int   v4i  __attribute__((ext_vector_type(4)));
typedef int   v16i __attribute__((ext_vector_type(16)));
typedef float v4f  __attribute__((ext_vector_type(4)));
typedef unsigned long long ull;

__device__ __forceinline__ v4i expand_bits(unsigned bits) {
  v4i a;
  a.x = (int)((( bits        & 15u) * 0x204081u) & 0x01010101u);
  a.y = (int)((((bits >>  4) & 15u) * 0x204081u) & 0x01010101u);
  a.z = (int)((((bits >>  8) & 15u) * 0x204081u) & 0x01010101u);
  a.w = (int)((((bits >> 12) & 15u) * 0x204081u) & 0x01010101u);
  return a;
}

// ---- merged front end: W2 digits | W3 digits | bit-exact layer-1 masks.
__global__ __launch_bounds__(256) void phase_front(const float* __restrict__ W2,
    const float* __restrict__ W3, const float* __restrict__ x,
    const float* __restrict__ W1, const float* __restrict__ b1,
    signed char* __restrict__ dig, signed char* __restrict__ w3d,
    ull* __restrict__ masks)
{
  const int blk = blockIdx.x, tid = threadIdx.x;
  if (blk < 2048) {
    // W2 -> 4 signed-i8 digit planes of llrint(w*2^32), layout
    // [stripe(8)][d(4)][s(16)][h(2)][n(32)][j(16)]; h1=s*32+h*16+j, h2=stripe*32+n
    int i = blk * 256 + tid;                       // [0, 524288)
    int j = i & 15, n = (i >> 4) & 31, h = (i >> 9) & 1;
    int s = (i >> 10) & 15, d = (i >> 14) & 3, st = i >> 16;
    int h1 = s * 32 + h * 16 + j;
    int h2 = st * 32 + n;
    float w = W2[h2 * HH1 + h1];
    long long ll = llrint((double)w * 4294967296.0);
    int v = (int)ll;
    signed char d0 = (signed char)(v & 255); v = (v - d0) >> 8;
    signed char d1 = (signed char)(v & 255); v = (v - d1) >> 8;
    signed char d2 = (signed char)(v & 255); v = (v - d2) >> 8;
    signed char d3 = (signed char)v;
    dig[i] = (d == 0) ? d0 : (d == 1) ? d1 : (d == 2) ? d2 : d3;
  } else if (blk < 2176) {
    // W3 digits, LDS image [d(4)][c8(8)][h(2)][col(32)][j(16)], 32 KB
    int i = (blk - 2048) * 256 + tid;              // [0, 32768)
    int j = i & 15, col = (i >> 4) & 31, h = (i >> 9) & 1;
    int c8 = (i >> 10) & 7, d = (i >> 13) & 3;
    int h2 = c8 * 32 + h * 16 + j;
    float w = (col < CC) ? W3[col * HH2 + h2] : 0.0f;
    long long ll = llrint((double)w * 4294967296.0);
    int v = (int)ll;
    signed char d0 = (signed char)(v & 255); v = (v - d0) >> 8;
    signed char d1 = (signed char)(v & 255); v = (v - d1) >> 8;
    signed char d2 = (signed char)(v & 255); v = (v - d2) >> 8;
    signed char d3 = (signed char)v;
    w3d[i] = (d == 0) ? d0 : (d == 1) ? d1 : (d == 2) ? d2 : d3;
  } else {
    // bit-exact layer 1 (mul-rn, add-rn, add-rn), one block per row
    __shared__ float xrow[TT];
    const int row = blk - 2176, wv = tid >> 6, lane = tid & 63;
    for (int i = tid; i < TT; i += 256) xrow[i] = x[row * TT + i];
    const float w1a = W1[tid], w1b = W1[tid + 256];
    const float b1a = b1[tid], b1b = b1[tid + 256];
    float v1a = 0.f, v1b = 0.f;
    __syncthreads();
    for (int t = 0; t < TT; ++t) {
      float xt = xrow[t];
      float iA = __fadd_rn(__fmul_rn(xt, w1a), b1a);
      v1a = __fadd_rn(v1a, iA);
      bool sA = (v1a >= 1.0f);  v1a = sA ? (v1a - 1.0f) : v1a;
      float iB = __fadd_rn(__fmul_rn(xt, w1b), b1b);
      v1b = __fadd_rn(v1b, iB);
      bool sB = (v1b >= 1.0f);  v1b = sB ? (v1b - 1.0f) : v1b;
      ull mA = __ballot(sA);
      ull mB = __ballot(sB);
      if (lane == 0) {
        ull* p = masks + ((size_t)t * BB + row) * 8;
        p[wv] = mA; p[4 + wv] = mB;
      }
    }
  }
}

// ---- fused layer 2: producer-consumer, spill-proofed.
// 512 threads = 8 waves, __launch_bounds__(512,2) pins 2 waves/SIMD so the
// 128-VGPR accumulator file stays register-resident (R8/R11 spilled at
// default occupancy). Waves 0-3: GEMM, wave wv owns t = tb+wv, tb+4+wv
// (2 t x 4 digit planes: 768 B/MFMA LDS supply < matrix-pipe time), with
// next-chunk mask prefetch in regs. Waves 4-7: v2-scan of chunk c-1.
// d2buf col-stride 33: conflict-free b128 writes/reads.
__global__ __launch_bounds__(512, 2) void phase_gemmscan(
    const signed char* __restrict__ Bd, const ull* __restrict__ masks,
    const float* __restrict__ b2, unsigned* __restrict__ masks2)
{
  __shared__ __align__(16) signed char Bl[65536];
  __shared__ float d2buf[2][8][32 * 33];           // [dbuf][tl][col*33+rowl] 67.6 KB

  const int bid = blockIdx.x;
  const int rowtile = bid & 31, stripe = bid >> 5; // stripe-siblings: same XCD
  const int tid = threadIdx.x, lane = tid & 63, wv = tid >> 6;
  const int half = lane >> 5;

  {
    const uint4* src = (const uint4*)(Bd + (size_t)stripe * 65536);
    uint4* dst = (uint4*)Bl;
#pragma unroll
    for (int i = 0; i < 8; ++i) dst[tid + 512 * i] = src[tid + 512 * i];
  }

  // GEMM-wave constants (wv < 4)
  const int arow = rowtile * 32 + (lane & 31);
  const int hsh  = half * 16;
  const signed char* bbase = Bl + half * 512 + (lane & 31) * 16;

  // scan-wave constants (wv >= 4)
  const int stid = tid - 256;                      // 0..255 for waves 4-7
  const int scol = stid & 31, sgrp = stid >> 5;    // col, 4-row group
  float v2[4] = {0.f, 0.f, 0.f, 0.f};
  float b2r = 0.f;
  if (wv >= 4) b2r = b2[stripe * 32 + scol];

  // prefetch chunk-0 masks (t = wv and wv+4)
  ull pmA[8], pmB[8];
  if (wv < 4) {
    const ull* pa = masks + ((size_t)wv * BB + arow) * 8;
    const ull* pb = masks + ((size_t)(wv + 4) * BB + arow) * 8;
#pragma unroll
    for (int k = 0; k < 8; ++k) { pmA[k] = pa[k]; pmB[k] = pb[k]; }
  }

  __syncthreads();                                 // Bl ready

  for (int c = 0; c < 17; ++c) {
    if (wv < 4 && c < 16) {
      ull wA[8], wB[8];
#pragma unroll
      for (int k = 0; k < 8; ++k) { wA[k] = pmA[k]; wB[k] = pmB[k]; }
      // issue next-chunk mask loads now; consumed after the MFMA loop
      const int cn = (c + 1 < 16) ? c + 1 : 15;
      { const ull* pa = masks + ((size_t)(cn * 8 + wv) * BB + arow) * 8;
        const ull* pb = masks + ((size_t)(cn * 8 + 4 + wv) * BB + arow) * 8;
#pragma unroll
        for (int k = 0; k < 8; ++k) { pmA[k] = pa[k]; pmB[k] = pb[k]; }
      }

      v16i accA[4], accB[4];
#pragma unroll
      for (int d = 0; d < 4; ++d) {
        accA[d] = (v16i){0,0,0,0,0,0,0,0,0,0,0,0,0,0,0,0};
        accB[d] = (v16i){0,0,0,0,0,0,0,0,0,0,0,0,0,0,0,0};
      }
#pragma unroll
      for (int s = 0; s < 16; ++s) {
        v4i q0 = *(const v4i*)(bbase + (0 * 16 + s) * 1024);
        v4i q1 = *(const v4i*)(bbase + (1 * 16 + s) * 1024);
        v4i q2 = *(const v4i*)(bbase + (2 * 16 + s) * 1024);
        v4i q3 = *(const v4i*)(bbase + (3 * 16 + s) * 1024);
        unsigned shift = ((s & 1) << 5) + hsh;
        v4i aA = expand_bits((unsigned)(wA[s >> 1] >> shift) & 0xFFFFu);
        v4i aB = expand_bits((unsigned)(wB[s >> 1] >> shift) & 0xFFFFu);
        accA[0] = __builtin_amdgcn_mfma_i32_32x32x32_i8(aA, q0, accA[0], 0, 0, 0);
        accB[0] = __builtin_amdgcn_mfma_i32_32x32x32_i8(aB, q0, accB[0], 0, 0, 0);
        accA[1] = __builtin_amdgcn_mfma_i32_32x32x32_i8(aA, q1, accA[1], 0, 0, 0);
        accB[1] = __builtin_amdgcn_mfma_i32_32x32x32_i8(aB, q1, accB[1], 0, 0, 0);
        accA[2] = __builtin_amdgcn_mfma_i32_32x32x32_i8(aA, q2, accA[2], 0, 0, 0);
        accB[2] = __builtin_amdgcn_mfma_i32_32x32x32_i8(aB, q2, accB[2], 0, 0, 0);
        accA[3] = __builtin_amdgcn_mfma_i32_32x32x32_i8(aA, q3, accA[3], 0, 0, 0);
        accB[3] = __builtin_amdgcn_mfma_i32_32x32x32_i8(aB, q3, accB[3], 0, 0, 0);
      }
      // exact digit fold -> one f32 rounding (bit-identical to R4 path);
      // vectorized b128 stores (4 consecutive rowl per r-group)
      float* bufA = d2buf[c & 1][wv];
      float* bufB = d2buf[c & 1][wv + 4];
#pragma unroll
      for (int g = 0; g < 4; ++g) {
        v4f fa, fb;
#pragma unroll
        for (int u = 0; u < 4; ++u) {
          int r = g * 4 + u;
          int sloA = accA[0][r] + (accA[1][r] << 8);   // exact i32, |.| < 2^25
          int shiA = accA[2][r] + (accA[3][r] << 8);
          double ssA = fma((double)shiA, 65536.0, (double)sloA);  // exact
          fa[u] = (float)(ssA * 0x1p-32);                         // one rounding
          int sloB = accB[0][r] + (accB[1][r] << 8);
          int shiB = accB[2][r] + (accB[3][r] << 8);
          double ssB = fma((double)shiB, 65536.0, (double)sloB);
          fb[u] = (float)(ssB * 0x1p-32);
        }
        int base = (lane & 31) * 33 + 8 * g + 4 * half;
        *(v4f*)&bufA[base] = fa;
        *(v4f*)&bufB[base] = fb;
      }
    }
    if (wv >= 4 && c > 0) {
      const int tb = (c - 1) * 8;
      const int rb = (c - 1) & 1;
      for (int tl = 0; tl < 8; ++tl) {
        const int t = tb + tl;
        v4f d4 = *(const v4f*)&d2buf[rb][tl][scol * 33 + sgrp * 4];
#pragma unroll
        for (int q = 0; q < 4; ++q) {
          float i2 = __fadd_rn(d4[q], b2r);
          v2[q] = __fadd_rn(v2[q], i2);
          bool s2 = (v2[q] >= 1.0f);
          v2[q] = s2 ? (v2[q] - 1.0f) : v2[q];
          ull m = __ballot(s2);                    // lo32: even sgrp, hi32: odd
          if (lane == 0)
            masks2[((size_t)t * BB + rowtile * 32 + sgrp * 4 + q) * 8 + stripe]
                = (unsigned)m;
          else if (lane == 32)
            masks2[((size_t)t * BB + rowtile * 32 + sgrp * 4 + q) * 8 + stripe]
                = (unsigned)(m >> 32);
        }
      }
    }
    __syncthreads();
  }
}

// ---- layer 3: D3[t] = S2[t] @ W3^T, exact i8 MFMA. Block: 32 rows x 4 t.
__global__ __launch_bounds__(256) void phase_l3(const signed char* __restrict__ W3d,
    const unsigned* __restrict__ masks2, float* __restrict__ D3)
{
  __shared__ __align__(16) signed char Bl[32768];
  const int bid = blockIdx.x;
  const int rowtile = bid & 31, tgrp = bid >> 5;
  const int tid = threadIdx.x, lane = tid & 63, wv = tid >> 6;
  const int half = lane >> 5;
  const int t = tgrp * 4 + wv;
  const int row = rowtile * 32 + (lane & 31);

  {
    const uint4* src = (const uint4*)W3d;
    uint4* dst = (uint4*)Bl;
#pragma unroll
    for (int i = 0; i < 8; ++i) dst[tid + 256 * i] = src[tid + 256 * i];
  }

  unsigned words[8];
  {
    const unsigned* mp = masks2 + ((size_t)t * BB + row) * 8;
#pragma unroll
    for (int k = 0; k < 8; ++k) words[k] = mp[k];
  }
  __syncthreads();

  const signed char* bbase = Bl + half * 512 + (lane & 31) * 16;
  v16i acc[4];
#pragma unroll
  for (int d = 0; d < 4; ++d) acc[d] = (v16i){0,0,0,0,0,0,0,0,0,0,0,0,0,0,0,0};

#pragma unroll
  for (int c8 = 0; c8 < 8; ++c8) {
    v4i a = expand_bits((words[c8] >> (half * 16)) & 0xFFFFu);
#pragma unroll
    for (int d = 0; d < 4; ++d) {
      v4i b = *(const v4i*)(bbase + ((d * 8 + c8) * 2) * 512);
      acc[d] = __builtin_amdgcn_mfma_i32_32x32x32_i8(a, b, acc[d], 0, 0, 0);
    }
  }

  const int col = lane & 31;
#pragma unroll
  for (int r = 0; r < 16; ++r) {
    int slo = acc[0][r] + (acc[1][r] << 8);
    int shi = acc[2][r] + (acc[3][r] << 8);
    double ss = fma((double)shi, 65536.0, (double)slo);
    float d3v = (float)(ss * 0x1p-32);
    int rowl = (r & 3) + 8 * (r >> 2) + 4 * half;
    int grow = rowtile * 32 + rowl;
    if (col < CC) D3[((size_t)t * BB + grow) * CC + col] = d3v;
  }
}

// ---- v3/acc scan + output. thread=(row,c); 4-deep prefetch ring; grid 72.
__global__ __launch_bounds__(256) void phase_v3(const float* __restrict__ D3,
    const float* __restrict__ b3, float* __restrict__ out)
{
  int g = blockIdx.x * 256 + threadIdx.x;         // [0, 18432)
  int row = g / CC, c = g - row * CC;
  const float b3r = b3[c];
  float v3 = 0.f, acc = 0.f;
  float buf[4];
#pragma unroll
  for (int p = 0; p < 4; ++p) buf[p] = D3[(size_t)p * (BB * CC) + g];
  for (int t = 0; t < TT; ++t) {
    float d3 = buf[t & 3];
    if (t + 4 < TT) buf[t & 3] = D3[(size_t)(t + 4) * (BB * CC) + g];
    float i3 = __fadd_rn(d3, b3r);
    v3 = __fadd_rn(v3, i3);
    bool s3 = (v3 >= 1.0f);  v3 = s3 ? (v3 - 1.0f) : v3;
    acc = __fadd_rn(acc, s3 ? 1.0f : 0.0f);
  }
  out[g] = acc * (1.0f / TT);
}

extern "C" void kernel_launch(void* const* d_in, const int* in_sizes, int n_in,
                              void* d_out, int out_size, void* d_ws, size_t ws_size,
                              hipStream_t stream)
{
  (void)in_sizes; (void)n_in; (void)out_size; (void)ws_size;
  const float* x  = (const float*)d_in[0];
  const float* W1 = (const float*)d_in[1];
  const float* b1 = (const float*)d_in[2];
  const float* W2 = (const float*)d_in[3];
  const float* b2 = (const float*)d_in[4];
  const float* W3 = (const float*)d_in[5];
  const float* b3 = (const float*)d_in[6];
  // d_in[7] = repeat (structurally 1 for this problem shape)
  float* out = (float*)d_out;
  char*  ws  = (char*)d_ws;

  signed char* dig    = (signed char*)(ws + WS_DIG);
  signed char* w3dig  = (signed char*)(ws + WS_W3D);
  ull*         masks  = (ull*)(ws + WS_MASK);
  unsigned*    masks2 = (unsigned*)(ws + WS_MASK2);
  float*       D3     = (float*)(ws + WS_D3);

  phase_front<<<3200, 256, 0, stream>>>(W2, W3, x, W1, b1, dig, w3dig, masks);
  phase_gemmscan<<<256, 512, 0, stream>>>(dig, masks, b2, masks2);
  phase_l3<<<1024, 256, 0, stream>>>(w3dig, masks2, D3);
  phase_v3<<<72, 256, 0, stream>>>(D3, b3, out);
}